// Round 3
// baseline (1394.495 us; speedup 1.0000x reference)
//
#include <hip/hip_runtime.h>
#include <hip/hip_bf16.h>
#include <cstdint>
#include <cstddef>

typedef unsigned short u16;
typedef __attribute__((ext_vector_type(8))) __bf16 bf16x8;
typedef __attribute__((ext_vector_type(4))) float floatx4;

#define B_ 8
#define S_ 2048
#define D_ 1024
#define H_ 4096
#define E_ 8

__device__ __forceinline__ u16 f2bf(float f) {
    union { float f; unsigned u; } c; c.f = f;
    return (u16)((c.u + 0x7fffu + ((c.u >> 16) & 1u)) >> 16);  // RNE, finite inputs
}

__device__ __forceinline__ void gload16(const void* g, void* l) {
    __builtin_amdgcn_global_load_lds((__attribute__((address_space(1))) void*)(g),
                                     (__attribute__((address_space(3))) void*)(l),
                                     16, 0, 0);
}

// ---- LDS tile layout (shared by all staging paths + fragld) ----
// 1024 slots of 8 bf16 (16B). Slot j holds source (row r=j>>3, chunk c=(j&7)^(r&7)).
// -> swizzled: data(row, chunk c) lives at slot (row<<3) + (c ^ (row&7)).

// Stage 128x64 bf16 row-major tile via global_load_lds (fast path).
__device__ __forceinline__ void stage(const u16* gbase, int ld, u16* lds, int tid) {
    int wid = tid >> 6;
#pragma unroll
    for (int q = 0; q < 4; ++q) {
        int j = q * 256 + tid;
        int r = j >> 3;
        int c = (j & 7) ^ (r & 7);
        gload16(gbase + (size_t)r * ld + c * 8,
                lds + (size_t)(q * 256 + wid * 64) * 8);
    }
}

// Stage 128x64 fp32 row-major tile, converting to bf16 (tier-C path).
__device__ __forceinline__ void stageF(const float* gbase, int ld, u16* lds, int tid) {
#pragma unroll
    for (int q = 0; q < 4; ++q) {
        int j = q * 256 + tid;
        int r = j >> 3;
        int c = (j & 7) ^ (r & 7);
        const float* src = gbase + (size_t)r * ld + c * 8;
        u16 tmp[8];
#pragma unroll
        for (int i = 0; i < 8; ++i) tmp[i] = f2bf(src[i]);
        *(uint4*)(lds + (size_t)j * 8) = *(uint4*)tmp;
    }
}

// Stage 64-krow x 128-ncol fp32 k-major tile into the same n-major layout
// via transposing scalar LDS writes (tier-C path, slow but correct).
__device__ __forceinline__ void stageKTF(const float* gbase, int ld, u16* lds, int tid) {
#pragma unroll
    for (int q = 0; q < 4; ++q) {
        int g = q * 256 + tid;          // granule 0..1023
        int k = g >> 4;                 // 0..63
        int nc = g & 15;                // n-chunk 0..15
        const float* src = gbase + (size_t)k * ld + nc * 8;
        int kc = k >> 3, kl = k & 7;
#pragma unroll
        for (int i = 0; i < 8; ++i) {
            int n = nc * 8 + i;
            lds[(((n << 3) + (kc ^ (n & 7))) << 3) + kl] = f2bf(src[i]);
        }
    }
}

__device__ __forceinline__ bf16x8 fragld(const u16* lds, int row, int c) {
    return *(const bf16x8*)(lds + (((row << 3) + (c ^ (row & 7))) << 3));
}

// ---------------- gate (fp32 throughout) ----------------
__global__ void mean_kernel(const float* __restrict__ x, float* __restrict__ ri) {
    int d = (blockIdx.x & 3) * 256 + threadIdx.x;
    int b = blockIdx.x >> 2;
    const float* p = x + (size_t)b * S_ * D_ + d;
    float s = 0.f;
#pragma unroll 8
    for (int i = 0; i < S_; ++i) s += p[(size_t)i * D_];
    ri[b * D_ + d] = s * (1.0f / S_);
}

__global__ void gate1_kernel(const float* __restrict__ ri, const float* __restrict__ Wg1,
                             const float* __restrict__ bg1, float* __restrict__ gh) {
    int j = (blockIdx.x & 3) * 256 + threadIdx.x;
    int b = blockIdx.x >> 2;
    const float* r = ri + b * D_;
    float acc = 0.f;
    for (int i = 0; i < D_; ++i) acc += r[i] * Wg1[(size_t)i * D_ + j];
    acc += bg1[j];
    gh[b * D_ + j] = acc / (1.f + expf(-acc));
}

__global__ void gate2_kernel(const float* __restrict__ gh, const float* __restrict__ Wg2,
                             const float* __restrict__ bg2, float* __restrict__ wgate,
                             int* __restrict__ eidx, float* __restrict__ out) {
    __shared__ float lg[B_ * E_];
    int t = threadIdx.x;  // 64 threads: (b,e) pairs
    int b = t >> 3, e = t & 7;
    const float* g = gh + b * D_;
    float acc = 0.f;
    for (int i = 0; i < D_; ++i) acc += g[i] * Wg2[(size_t)i * E_ + e];
    acc += bg2[e];
    lg[t] = acc;
    __syncthreads();
    if (t < B_) {
        float l0 = -1e30f, l1 = -1e30f; int i0 = 0, i1 = 0;
        for (int ee = 0; ee < E_; ++ee) {
            float v = lg[t * E_ + ee];
            if (v > l0) { l1 = l0; i1 = i0; l0 = v; i0 = ee; }
            else if (v > l1) { l1 = v; i1 = ee; }
        }
        float e1 = expf(l1 - l0);
        float w0 = 1.f / (1.f + e1), w1 = e1 / (1.f + e1);
        wgate[t * 2] = w0; wgate[t * 2 + 1] = w1;
        eidx[t * 2] = i0;  eidx[t * 2 + 1] = i1;
        float* ow = out + (size_t)B_ * S_ * D_;        // tail: topk_w then topk_idx
        ow[t * 2] = w0;              ow[t * 2 + 1] = w1;
        ow[16 + t * 2] = (float)i0;  ow[16 + t * 2 + 1] = (float)i1;
    }
}

// ---------------- converters (tier A) ----------------
__global__ void convx_kernel(const float* __restrict__ in, u16* __restrict__ out) {
    size_t i = ((size_t)blockIdx.x * 256 + threadIdx.x) * 8;
    u16 tmp[8];
#pragma unroll
    for (int j = 0; j < 8; ++j) tmp[j] = f2bf(in[i + j]);
    *(uint4*)(out + i) = *(uint4*)tmp;
}

// in fp32 [E][R][C] -> out bf16 [E][C][R]
__global__ __launch_bounds__(256) void convT_kernel(const float* __restrict__ in,
                                                    u16* __restrict__ out,
                                                    int R, int C) {
    __shared__ __align__(16) u16 T[64][72];
    int e = blockIdx.z;
    const float* ine = in + (size_t)e * R * C;
    u16* oute = out + (size_t)e * R * C;
    int r0 = blockIdx.y * 64, c0 = blockIdx.x * 64;
    int tid = threadIdx.x;
#pragma unroll
    for (int q = 0; q < 2; ++q) {
        int j = q * 256 + tid;
        int r = j >> 3, ch = j & 7;
        const float* src = ine + (size_t)(r0 + r) * C + c0 + ch * 8;
        u16 tmp[8];
#pragma unroll
        for (int i = 0; i < 8; ++i) tmp[i] = f2bf(src[i]);
        *(uint4*)&T[r][ch * 8] = *(uint4*)tmp;
    }
    __syncthreads();
#pragma unroll
    for (int q = 0; q < 2; ++q) {
        int j = q * 256 + tid;
        int orow = j >> 3, och = j & 7;
        uint4 v; u16* pv = (u16*)&v;
#pragma unroll
        for (int i = 0; i < 8; ++i) pv[i] = T[och * 8 + i][orow];
        *(uint4*)(oute + (size_t)(c0 + orow) * R + r0 + och * 8) = v;
    }
}

// ---------------- GEMM1: h[lp] = topk_w[p] * silu(x[b] @ W1[e] + b1[e]) ----------------
// BT=0: A = xb bf16 [B*S][D], Bw = W1T bf16 [E][H][D].
// BT=1: A = x fp32 [B*S][D],  Bw = W1 fp32 [E][D][H].
template<int BT>
__global__ __launch_bounds__(256) void gemm1_kernel(
    const void* __restrict__ A_, const void* __restrict__ Bw_,
    const float* __restrict__ b1, const int* __restrict__ eidx,
    const float* __restrict__ wgate, u16* __restrict__ hbuf,
    int s0, int hRows, int pbase) {
    __shared__ __align__(16) u16 ldsA[1024 * 8];
    __shared__ __align__(16) u16 ldsB[1024 * 8];
    int tid = threadIdx.x, lane = tid & 63, wid = tid >> 6;
    int wm = wid & 1, wn = wid >> 1, lr = lane & 15, quad = lane >> 4;
    int lp = blockIdx.z, p = pbase + lp, b = p >> 1;
    int e = eidx[p];
    float wk = wgate[p];
    size_t arow = (size_t)(b * S_ + s0 + blockIdx.y * 128);
    floatx4 acc[4][4] = {};
    for (int kk = 0; kk < D_; kk += 64) {
        if (BT == 0) {
            stage((const u16*)A_ + arow * D_ + kk, D_, ldsA, tid);
            stage((const u16*)Bw_ + (size_t)e * H_ * D_ +
                  (size_t)(blockIdx.x * 128) * D_ + kk, D_, ldsB, tid);
        } else {
            stageF((const float*)A_ + arow * D_ + kk, D_, ldsA, tid);
            stageKTF((const float*)Bw_ + (size_t)e * D_ * H_ +
                     (size_t)kk * H_ + blockIdx.x * 128, H_, ldsB, tid);
        }
        __syncthreads();
#pragma unroll
        for (int ks = 0; ks < 2; ++ks) {
            bf16x8 af[4], bfr[4];
#pragma unroll
            for (int t = 0; t < 4; ++t) {
                af[t]  = fragld(ldsA, wm * 64 + t * 16 + lr, ks * 4 + quad);
                bfr[t] = fragld(ldsB, wn * 64 + t * 16 + lr, ks * 4 + quad);
            }
#pragma unroll
            for (int mt = 0; mt < 4; ++mt)
#pragma unroll
                for (int nt = 0; nt < 4; ++nt)
                    acc[mt][nt] = __builtin_amdgcn_mfma_f32_16x16x32_bf16(
                        af[mt], bfr[nt], acc[mt][nt], 0, 0, 0);
        }
        __syncthreads();
    }
#pragma unroll
    for (int mt = 0; mt < 4; ++mt)
#pragma unroll
        for (int nt = 0; nt < 4; ++nt) {
            int n = blockIdx.x * 128 + wn * 64 + nt * 16 + lr;
            float bb = b1[e * H_ + n];
#pragma unroll
            for (int r = 0; r < 4; ++r) {
                int mrow = blockIdx.y * 128 + wm * 64 + mt * 16 + quad * 4 + r;
                float v = acc[mt][nt][r] + bb;
                v = v / (1.f + __expf(-v)) * wk;
                hbuf[((size_t)lp * hRows + mrow) * H_ + n] = f2bf(v);
            }
        }
}

// ---------------- GEMM2: out[b] = sum_k h[lb*2+k] @ W2[e_k] + sum_k w_k*b2[e_k] ----------------
// BT=0: Bw = W2T bf16 [E][D][H].  BT=1: Bw = W2 fp32 [E][H][D].
template<int BT>
__global__ __launch_bounds__(256) void gemm2_kernel(
    const u16* __restrict__ hbuf, const void* __restrict__ Bw_,
    const float* __restrict__ b2, const int* __restrict__ eidx,
    const float* __restrict__ wgate, float* __restrict__ out,
    int s0, int hRows, int bbase) {
    __shared__ __align__(16) u16 ldsA[1024 * 8];
    __shared__ __align__(16) u16 ldsB[1024 * 8];
    int tid = threadIdx.x, lane = tid & 63, wid = tid >> 6;
    int wm = wid & 1, wn = wid >> 1, lr = lane & 15, quad = lane >> 4;
    int lb = blockIdx.z, b = bbase + lb;
    floatx4 acc[4][4] = {};
    for (int kp = 0; kp < 2; ++kp) {
        int e = eidx[b * 2 + kp];
        const u16* Abase = hbuf + ((size_t)(lb * 2 + kp) * hRows + blockIdx.y * 128) * H_;
        for (int kk = 0; kk < H_; kk += 64) {
            stage(Abase + kk, H_, ldsA, tid);
            if (BT == 0)
                stage((const u16*)Bw_ + (size_t)e * D_ * H_ +
                      (size_t)(blockIdx.x * 128) * H_ + kk, H_, ldsB, tid);
            else
                stageKTF((const float*)Bw_ + (size_t)e * H_ * D_ +
                         (size_t)kk * D_ + blockIdx.x * 128, D_, ldsB, tid);
            __syncthreads();
#pragma unroll
            for (int ks = 0; ks < 2; ++ks) {
                bf16x8 af[4], bfr[4];
#pragma unroll
                for (int t = 0; t < 4; ++t) {
                    af[t]  = fragld(ldsA, wm * 64 + t * 16 + lr, ks * 4 + quad);
                    bfr[t] = fragld(ldsB, wn * 64 + t * 16 + lr, ks * 4 + quad);
                }
#pragma unroll
                for (int mt = 0; mt < 4; ++mt)
#pragma unroll
                    for (int nt = 0; nt < 4; ++nt)
                        acc[mt][nt] = __builtin_amdgcn_mfma_f32_16x16x32_bf16(
                            af[mt], bfr[nt], acc[mt][nt], 0, 0, 0);
            }
            __syncthreads();
        }
    }
    int e0 = eidx[b * 2], e1 = eidx[b * 2 + 1];
    float w0 = wgate[b * 2], w1 = wgate[b * 2 + 1];
#pragma unroll
    for (int mt = 0; mt < 4; ++mt)
#pragma unroll
        for (int nt = 0; nt < 4; ++nt) {
            int n = blockIdx.x * 128 + wn * 64 + nt * 16 + lr;
            float bb = w0 * b2[e0 * D_ + n] + w1 * b2[e1 * D_ + n];
#pragma unroll
            for (int r = 0; r < 4; ++r) {
                int mrow = blockIdx.y * 128 + wm * 64 + mt * 16 + quad * 4 + r;
                out[((size_t)b * S_ + s0 + mrow) * D_ + n] = acc[mt][nt][r] + bb;
            }
        }
}

extern "C" void kernel_launch(void* const* d_in, const int* in_sizes, int n_in,
                              void* d_out, int out_size, void* d_ws, size_t ws_size,
                              hipStream_t stream) {
    const float* x   = (const float*)d_in[0];
    const float* Wg1 = (const float*)d_in[1];
    const float* bg1 = (const float*)d_in[2];
    const float* Wg2 = (const float*)d_in[3];
    const float* bg2 = (const float*)d_in[4];
    const float* W1  = (const float*)d_in[5];
    const float* b1  = (const float*)d_in[6];
    const float* W2  = (const float*)d_in[7];
    const float* b2  = (const float*)d_in[8];
    float* out = (float*)d_out;
    char* ws = (char*)d_ws;

    float* ri    = (float*)ws;                 // 32 KB
    float* gh    = (float*)(ws + 32768);       // 32 KB
    float* wgate = (float*)(ws + 65536);       // 64 B
    int*   eidx  = (int*)(ws + 65792);         // 64 B

    const size_t base = (size_t)1 << 20;                  // 1 MiB small-buffer region
    const size_t szXb = (size_t)B_ * S_ * D_ * 2;         // 32 MiB bf16 x
    const size_t szW  = (size_t)E_ * D_ * H_ * 2;         // 64 MiB per bf16 weight set
    const size_t rowB = (size_t)H_ * 2;                   // 8 KiB per hbuf row

    mean_kernel<<<dim3(B_ * 4), 256, 0, stream>>>(x, ri);
    gate1_kernel<<<dim3(B_ * 4), 256, 0, stream>>>(ri, Wg1, bg1, gh);
    gate2_kernel<<<1, 64, 0, stream>>>(gh, Wg2, bg2, wgate, eidx, out);

    auto clampSc = [](long v) -> int {
        long s = v & ~127L;
        if (s > S_) s = S_;
        if (s < 128) s = 128;
        return (int)s;
    };

    if (ws_size >= base + szXb + 2 * szW + (size_t)16 * 128 * rowB) {
        // ---- Tier A: bf16 x + both transposed bf16 weight copies + hbuf ----
        u16* xb   = (u16*)(ws + base);
        u16* W1T  = (u16*)(ws + base + szXb);
        u16* W2T  = (u16*)(ws + base + szXb + szW);
        u16* hbuf = (u16*)(ws + base + szXb + 2 * szW);
        int Sc = clampSc((long)((ws_size - base - szXb - 2 * szW) / ((size_t)16 * rowB)));
        convx_kernel<<<dim3((B_ * S_ * D_) / (256 * 8)), 256, 0, stream>>>(x, xb);
        convT_kernel<<<dim3(H_ / 64, D_ / 64, E_), 256, 0, stream>>>(W1, W1T, D_, H_);
        convT_kernel<<<dim3(D_ / 64, H_ / 64, E_), 256, 0, stream>>>(W2, W2T, H_, D_);
        for (int s0 = 0; s0 < S_; s0 += Sc) {
            int rows = (S_ - s0 < Sc) ? (S_ - s0) : Sc;
            gemm1_kernel<0><<<dim3(H_ / 128, rows / 128, B_ * 2), 256, 0, stream>>>(
                xb, W1T, b1, eidx, wgate, hbuf, s0, Sc, 0);
            gemm2_kernel<0><<<dim3(D_ / 128, rows / 128, B_), 256, 0, stream>>>(
                hbuf, W2T, b2, eidx, wgate, out, s0, Sc, 0);
        }
    } else {
        // ---- Tier C: no conversion buffers; stage fp32->bf16 through LDS ----
        u16* hbuf = (u16*)(ws + base);
        long avail = (long)ws_size - (long)base;
        if (avail < 0) avail = 0;
        int Sc = clampSc(avail / (long)(2 * rowB));
        for (int b = 0; b < B_; ++b) {
            for (int s0 = 0; s0 < S_; s0 += Sc) {
                int rows = (S_ - s0 < Sc) ? (S_ - s0) : Sc;
                gemm1_kernel<1><<<dim3(H_ / 128, rows / 128, 2), 256, 0, stream>>>(
                    x, W1, b1, eidx, wgate, hbuf, s0, Sc, b * 2);
                gemm2_kernel<1><<<dim3(D_ / 128, rows / 128, 1), 256, 0, stream>>>(
                    hbuf, W2, b2, eidx, wgate, out, s0, Sc, b);
            }
        }
    }
}